// Round 3
// baseline (203.128 us; speedup 1.0000x reference)
//
#include <hip/hip_runtime.h>

// GCNCriticNet fused kernel, round 3.
// Identity: complete graph + self-loops => deg==16 => GCN agg == group mean.
// Mapping: 1024 blocks x 256 threads; block = 8 groups.
//   lane r = tid&31 within a group: t = r>>1 (hid slice of 8), h = r&1.
//   h splits NODES (emb: 8 nodes each) and K (matvec: 64 rows each);
//   h-pairs are adjacent lanes -> __shfl_xor(.,1) combines (VALU/DPP, cheap).
// Weights are read straight from global (L1/L2-resident, TA coalesces the
// 16-distinct-address broadcast) -> LDS pipe only carries the tiny means
// array. 4 blocks/CU = 16 waves/CU for latency hiding.

#define N_GRAPHS   8192
#define NODES      16
#define OBSD       64
#define HIDD       128
#define GPB        8
#define BLOCK      256
#define NBLOCKS    (N_GRAPHS / GPB)   // 1024
#define NPT        8                  // nodes per thread
#define JPT        8                  // hid cols per thread

__device__ __forceinline__ void fma4(float4& a, float s, const float4& b) {
  a.x = fmaf(s, b.x, a.x); a.y = fmaf(s, b.y, a.y);
  a.z = fmaf(s, b.z, a.z); a.w = fmaf(s, b.w, a.w);
}
__device__ __forceinline__ void add4(float4& a, const float4& b) {
  a.x += b.x; a.y += b.y; a.z += b.z; a.w += b.w;
}
__device__ __forceinline__ void xor1_4(float4& a) {
  a.x += __shfl_xor(a.x, 1); a.y += __shfl_xor(a.y, 1);
  a.z += __shfl_xor(a.z, 1); a.w += __shfl_xor(a.w, 1);
}
// tanh(z) = 1 - 2/(e^{2z}+1)
__device__ __forceinline__ float fast_tanh(float z) {
  float e = __expf(2.0f * z);
  return 1.0f - 2.0f / (e + 1.0f);
}

__global__ __launch_bounds__(BLOCK, 4) void gcn_fused(
    const float* __restrict__ obs,
    const float* __restrict__ w_emb,
    const float* __restrict__ b_emb,
    const float* __restrict__ w_gcn,
    const float* __restrict__ b_gcn,
    const float* __restrict__ w_fc1,
    const float* __restrict__ b_fc1,
    float* __restrict__ out)
{
  // double-buffered group means; row pad +4 => per-g bases hit distinct banks
  __shared__ float sM[2][GPB][HIDD + 4];

  const int tid   = threadIdx.x;
  const int g     = tid >> 5;            // group in block (wave = 2 groups)
  const int r     = tid & 31;
  const int t     = r >> 1;              // hid-slice index
  const int h     = r & 1;               // node-half / k-half
  const int j0    = t * JPT;
  const int group = blockIdx.x * GPB + g;
  const int node0 = group * NODES + h * NPT;

  // ---- embedding: x[i][j] = b_emb[j] + sum_k obs[node][k] * w_emb[k][j] ----
  float4 xlo[NPT], xhi[NPT];
  {
    float4 be0 = *(const float4*)&b_emb[j0];
    float4 be1 = *(const float4*)&b_emb[j0 + 4];
    #pragma unroll
    for (int i = 0; i < NPT; ++i) { xlo[i] = be0; xhi[i] = be1; }
  }

  #pragma unroll 1
  for (int kc = 0; kc < OBSD / 4; ++kc) {
    // W rows kc*4..kc*4+3, cols [j0, j0+8): 16 distinct 16B addrs per wave,
    // 4-way lane-dup -> TA/L1 broadcast
    float4 wlo[4], whi[4];
    #pragma unroll
    for (int kk = 0; kk < 4; ++kk) {
      const float* row = &w_emb[(kc * 4 + kk) * HIDD + j0];
      wlo[kk] = *(const float4*)(row);
      whi[kk] = *(const float4*)(row + 4);
    }
    #pragma unroll
    for (int c = 0; c < 2; ++c) {        // nodes in chunks of 4 (reg pressure)
      float4 o[4];
      #pragma unroll
      for (int u = 0; u < 4; ++u)
        o[u] = *(const float4*)&obs[(node0 + c * 4 + u) * OBSD + kc * 4];
      #pragma unroll
      for (int u = 0; u < 4; ++u) {
        const int i = c * 4 + u;
        fma4(xlo[i], o[u].x, wlo[0]); fma4(xhi[i], o[u].x, whi[0]);
        fma4(xlo[i], o[u].y, wlo[1]); fma4(xhi[i], o[u].y, whi[1]);
        fma4(xlo[i], o[u].z, wlo[2]); fma4(xhi[i], o[u].z, whi[2]);
        fma4(xlo[i], o[u].w, wlo[3]); fma4(xhi[i], o[u].w, whi[3]);
      }
    }
  }

  // ---- GCN layers: x = tanh((mean_g x) @ W_l + b_l + x) ----
  #pragma unroll 1
  for (int l = 0; l < 2; ++l) {
    // partial mean over my 8 nodes, combine across h-pair, scale
    float4 slo = xlo[0], shi = xhi[0];
    #pragma unroll
    for (int i = 1; i < NPT; ++i) { add4(slo, xlo[i]); add4(shi, xhi[i]); }
    xor1_4(slo); xor1_4(shi);
    const float inv = 1.0f / 16.0f;
    slo.x *= inv; slo.y *= inv; slo.z *= inv; slo.w *= inv;
    shi.x *= inv; shi.y *= inv; shi.z *= inv; shi.w *= inv;
    if (h == 0) {
      *(float4*)&sM[l][g][j0]     = slo;
      *(float4*)&sM[l][g][j0 + 4] = shi;
    }
    __syncthreads();

    // matvec: my k-half, W from global (L2-resident, broadcast loads)
    const float* wl = w_gcn + l * HIDD * HIDD;
    float4 h0 = make_float4(0.f, 0.f, 0.f, 0.f);
    float4 h1 = make_float4(0.f, 0.f, 0.f, 0.f);
    const int kbase = h * 64;
    #pragma unroll 4
    for (int kr = 0; kr < 64; ++kr) {
      const int k = kbase + kr;
      const float mk = sM[l][g][k];                  // 2 distinct addrs/wave
      const float* row = &wl[k * HIDD + j0];
      float4 w0 = *(const float4*)(row);
      float4 w1 = *(const float4*)(row + 4);
      fma4(h0, mk, w0);
      fma4(h1, mk, w1);
    }
    // combine k-halves, add bias
    xor1_4(h0); xor1_4(h1);
    float4 bg0 = *(const float4*)&b_gcn[l * HIDD + j0];
    float4 bg1 = *(const float4*)&b_gcn[l * HIDD + j0 + 4];
    add4(h0, bg0); add4(h1, bg1);

    #pragma unroll
    for (int i = 0; i < NPT; ++i) {
      xlo[i].x = fast_tanh(h0.x + xlo[i].x);
      xlo[i].y = fast_tanh(h0.y + xlo[i].y);
      xlo[i].z = fast_tanh(h0.z + xlo[i].z);
      xlo[i].w = fast_tanh(h0.w + xlo[i].w);
      xhi[i].x = fast_tanh(h1.x + xhi[i].x);
      xhi[i].y = fast_tanh(h1.y + xhi[i].y);
      xhi[i].z = fast_tanh(h1.z + xhi[i].z);
      xhi[i].w = fast_tanh(h1.w + xhi[i].w);
    }
  }

  // ---- value head: out[group] = (mean_g x) . w_fc1 + b_fc1 ----
  float4 slo = xlo[0], shi = xhi[0];
  #pragma unroll
  for (int i = 1; i < NPT; ++i) { add4(slo, xlo[i]); add4(shi, xhi[i]); }
  xor1_4(slo); xor1_4(shi);                          // 16-node sums
  float4 wf0 = *(const float4*)&w_fc1[j0];
  float4 wf1 = *(const float4*)&w_fc1[j0 + 4];
  float acc = slo.x * wf0.x + slo.y * wf0.y + slo.z * wf0.z + slo.w * wf0.w
            + shi.x * wf1.x + shi.y * wf1.y + shi.z * wf1.z + shi.w * wf1.w;
  acc *= (1.0f / 16.0f);
  acc += __shfl_xor(acc, 2);
  acc += __shfl_xor(acc, 4);
  acc += __shfl_xor(acc, 8);
  acc += __shfl_xor(acc, 16);
  if (r == 0) out[group] = acc + b_fc1[0];
}

extern "C" void kernel_launch(void* const* d_in, const int* in_sizes, int n_in,
                              void* d_out, int out_size, void* d_ws, size_t ws_size,
                              hipStream_t stream) {
  const float* obs    = (const float*)d_in[0];   // [131072, 64]
  const float* w_emb  = (const float*)d_in[1];   // [64, 128]
  const float* b_emb  = (const float*)d_in[2];   // [128]
  const float* w_gcn  = (const float*)d_in[3];   // [2, 128, 128]
  const float* b_gcn  = (const float*)d_in[4];   // [2, 128]
  const float* w_fc1  = (const float*)d_in[5];   // [128, 1]
  const float* b_fc1  = (const float*)d_in[6];   // [1]
  // d_in[7], d_in[8]: edge_src/edge_dst — redundant (deg==16 uniform)
  float* out = (float*)d_out;                    // [8192]

  gcn_fused<<<NBLOCKS, BLOCK, 0, stream>>>(obs, w_emb, b_emb, w_gcn, b_gcn,
                                           w_fc1, b_fc1, out);
}

// Round 4
// 134.189 us; speedup vs baseline: 1.5137x; 1.5137x over previous
//
#include <hip/hip_runtime.h>

// GCNCriticNet, round 4: MFMA bf16 with 3-term hi/lo split (~f32 accuracy).
// deg==16 uniform => GCN agg == group mean (edge arrays dead).
// Wave = 1 group: A-rows = 16 nodes (emb) / 16 replicated mean-rows (matvec).
// x kept in MFMA C-layout (col=lane&15, row=quad*4+reg) for the whole net.

#define N_GRAPHS 8192
#define BLOCK    256
#define NBLOCKS  (N_GRAPHS / 4)   // 4 groups (waves) per block

typedef __attribute__((ext_vector_type(8))) short  short8;   // 8 bf16
typedef __attribute__((ext_vector_type(4))) float  floatx4;  // C/D frag

#define MFMA16(a, b, c) __builtin_amdgcn_mfma_f32_16x16x32_bf16((a), (b), (c), 0, 0, 0)

__device__ __forceinline__ unsigned fbits(float x) {
  union { float f; unsigned u; } v; v.f = x; return v.u;
}
__device__ __forceinline__ float bitsf(unsigned u) {
  union { float f; unsigned u; } v; v.u = u; return v.f;
}
// f32 -> (hi, lo) bf16: hi = truncate, lo = bf16(x - hi). x ≈ hi + lo with
// ~2^-17 rel error; 3-term MFMA (hh + lh + hl) then carries ~1e-4 abs error.
__device__ __forceinline__ void bsplit(float x, short& hi, short& lo) {
  unsigned hb = fbits(x) & 0xFFFF0000u;
  hi = (short)(hb >> 16);
  lo = (short)(fbits(x - bitsf(hb)) >> 16);
}
__device__ __forceinline__ float fast_tanh(float z) {
  float e = __expf(2.0f * z);
  return 1.0f - 2.0f / (e + 1.0f);
}

// Stage a [64 x 128] k-slab of W (f32, row-stride 128) into hi/lo bf16
// B-fragment tables. Octet O=(kc,q,nt,c), j contiguous => frag = 1 ds_read_b128.
// Source loads are lane-coalesced over n; dest writes are ds_write_b128.
__device__ __forceinline__ void stage_w(const float* __restrict__ W, int kbase,
                                        short8* __restrict__ sHi,
                                        short8* __restrict__ sLo, int tid) {
  #pragma unroll
  for (int it = 0; it < 4; ++it) {
    int O  = it * 256 + tid;
    int cc = O & 15;
    int nt = (O >> 4) & 7;
    int qq = (O >> 7) & 3;
    int kc = (O >> 9) & 1;
    const float* src = W + (kbase + kc * 32 + qq * 8) * 128 + nt * 16 + cc;
    short8 hi, lo;
    #pragma unroll
    for (int j = 0; j < 8; ++j) {
      short h, l;
      bsplit(src[j * 128], h, l);
      hi[j] = h; lo[j] = l;
    }
    sHi[O] = hi;
    sLo[O] = lo;
  }
}

__global__ __launch_bounds__(BLOCK, 2) void gcn_mfma(
    const float* __restrict__ obs,
    const float* __restrict__ w_emb,
    const float* __restrict__ b_emb,
    const float* __restrict__ w_gcn,
    const float* __restrict__ b_gcn,
    const float* __restrict__ w_fc1,
    const float* __restrict__ b_fc1,
    float* __restrict__ out)
{
  __shared__ short8 sHi[1024];      // 16 KB  B-frag hi table
  __shared__ short8 sLo[1024];      // 16 KB  B-frag lo table
  __shared__ float  sM[4][128];     // per-wave group mean (no barrier needed)

  const int tid = threadIdx.x;
  const int w   = tid >> 6;         // wave id = group in block
  const int L   = tid & 63;
  const int q   = L >> 4;           // quad
  const int c   = L & 15;           // col-in-tile / node row (A operand)
  const int group = blockIdx.x * 4 + w;

  // ---- issue obs loads early (HBM latency hides under W staging) ----
  // A[m=c][k=q*8+j] (+32 for second K-chunk): lane reads 16 f32.
  const float* orow = obs + (group * 16 + c) * 64 + q * 8;
  float4 o0 = *(const float4*)(orow);
  float4 o1 = *(const float4*)(orow + 4);
  float4 o2 = *(const float4*)(orow + 32);
  float4 o3 = *(const float4*)(orow + 36);

  stage_w(w_emb, 0, sHi, sLo, tid);   // w_emb is [64][128]: one slab
  __syncthreads();

  // ---- A frags (obs hi/lo) ----
  short8 a0h, a0l, a1h, a1l;
  {
    float t0[8] = {o0.x, o0.y, o0.z, o0.w, o1.x, o1.y, o1.z, o1.w};
    float t1[8] = {o2.x, o2.y, o2.z, o2.w, o3.x, o3.y, o3.z, o3.w};
    #pragma unroll
    for (int j = 0; j < 8; ++j) {
      short h, l;
      bsplit(t0[j], h, l); a0h[j] = h; a0l[j] = l;
      bsplit(t1[j], h, l); a1h[j] = h; a1l[j] = l;
    }
  }

  // ---- embedding: x = obs @ w_emb + b_emb, 8 N-tiles of 16 cols ----
  floatx4 x[8];
  #pragma unroll
  for (int nt = 0; nt < 8; ++nt) {
    float b = b_emb[nt * 16 + c];
    floatx4 acc = {b, b, b, b};       // per-col bias, all rows
    int O = (q << 7) + (nt << 4) + c; // kc=0
    short8 bh = sHi[O], bl = sLo[O];
    acc = MFMA16(a0h, bh, acc);
    acc = MFMA16(a0l, bh, acc);
    acc = MFMA16(a0h, bl, acc);
    bh = sHi[512 + O]; bl = sLo[512 + O];   // kc=1
    acc = MFMA16(a1h, bh, acc);
    acc = MFMA16(a1l, bh, acc);
    acc = MFMA16(a1h, bl, acc);
    x[nt] = acc;
  }

  // ---- GCN layers: x = tanh((mean_g x) @ W_l + b_l + x) ----
  #pragma unroll 1
  for (int l = 0; l < 2; ++l) {
    // group mean -> sM[w] (column sums via quad fold; q==0 lanes write)
    #pragma unroll
    for (int nt = 0; nt < 8; ++nt) {
      float s = x[nt][0] + x[nt][1] + x[nt][2] + x[nt][3];
      s += __shfl_xor(s, 16);
      s += __shfl_xor(s, 32);
      if (q == 0) sM[w][nt * 16 + c] = s * 0.0625f;
    }

    const float* wl = w_gcn + l * 16384;
    floatx4 h[8];
    #pragma unroll
    for (int nt = 0; nt < 8; ++nt) h[nt] = (floatx4){0.f, 0.f, 0.f, 0.f};

    #pragma unroll 1
    for (int half = 0; half < 2; ++half) {
      __syncthreads();                      // everyone done with prev tables
      stage_w(wl, half * 64, sHi, sLo, tid);
      __syncthreads();
      #pragma unroll
      for (int kc = 0; kc < 2; ++kc) {
        // A = mean replicated across all 16 rows: frag depends only on k
        const float* mp = &sM[w][half * 64 + kc * 32 + q * 8];
        float4 m0 = *(const float4*)(mp);
        float4 m1 = *(const float4*)(mp + 4);
        float tm[8] = {m0.x, m0.y, m0.z, m0.w, m1.x, m1.y, m1.z, m1.w};
        short8 ah, al;
        #pragma unroll
        for (int j = 0; j < 8; ++j) {
          short hh, ll;
          bsplit(tm[j], hh, ll);
          ah[j] = hh; al[j] = ll;
        }
        #pragma unroll
        for (int nt = 0; nt < 8; ++nt) {
          int O = (kc << 9) + (q << 7) + (nt << 4) + c;
          short8 bh = sHi[O], bl = sLo[O];
          h[nt] = MFMA16(ah, bh, h[nt]);
          h[nt] = MFMA16(al, bh, h[nt]);
          h[nt] = MFMA16(ah, bl, h[nt]);
        }
      }
    }

    #pragma unroll
    for (int nt = 0; nt < 8; ++nt) {
      // rows of h are replicated => any component; add bias, residual, tanh
      float hb = h[nt][0] + b_gcn[l * 128 + nt * 16 + c];
      x[nt][0] = fast_tanh(x[nt][0] + hb);
      x[nt][1] = fast_tanh(x[nt][1] + hb);
      x[nt][2] = fast_tanh(x[nt][2] + hb);
      x[nt][3] = fast_tanh(x[nt][3] + hb);
    }
  }

  // ---- value head: out[group] = (1/16) sum_{row,col} x * w_fc1[col] + b ----
  float v = 0.f;
  #pragma unroll
  for (int nt = 0; nt < 8; ++nt)
    v += (x[nt][0] + x[nt][1] + x[nt][2] + x[nt][3]) * w_fc1[nt * 16 + c];
  v *= 0.0625f;
  v += __shfl_xor(v, 1);
  v += __shfl_xor(v, 2);
  v += __shfl_xor(v, 4);
  v += __shfl_xor(v, 8);
  v += __shfl_xor(v, 16);
  v += __shfl_xor(v, 32);
  if (L == 0) out[group] = v + b_fc1[0];
}

extern "C" void kernel_launch(void* const* d_in, const int* in_sizes, int n_in,
                              void* d_out, int out_size, void* d_ws, size_t ws_size,
                              hipStream_t stream) {
  const float* obs    = (const float*)d_in[0];   // [131072, 64]
  const float* w_emb  = (const float*)d_in[1];   // [64, 128]
  const float* b_emb  = (const float*)d_in[2];   // [128]
  const float* w_gcn  = (const float*)d_in[3];   // [2, 128, 128]
  const float* b_gcn  = (const float*)d_in[4];   // [2, 128]
  const float* w_fc1  = (const float*)d_in[5];   // [128, 1]
  const float* b_fc1  = (const float*)d_in[6];   // [1]
  // d_in[7], d_in[8]: edge_src/edge_dst — redundant (deg==16 uniform)
  float* out = (float*)d_out;                    // [8192]

  gcn_mfma<<<NBLOCKS, BLOCK, 0, stream>>>(obs, w_emb, b_emb, w_gcn, b_gcn,
                                          w_fc1, b_fc1, out);
}

// Round 5
// 122.632 us; speedup vs baseline: 1.6564x; 1.0942x over previous
//
#include <hip/hip_runtime.h>

// GCNCriticNet, round 5.
// deg==16 uniform => GCN agg == group mean (edge arrays dead).
// Prep kernel: convert weights ONCE to hi/lo bf16 MFMA B-frag tables in d_ws.
// Main kernel: block = 8 groups, 4 waves; emb via 32x32x16 (2 groups/wave);
// layer matvec block-batched: A rows = 8 group means, waves split N-tiles.
// B-frags read straight from global (L1/L2-resident, 1KB/wave-instr).
// 3-term hi/lo split (hh + lh + hl) ~ f32 accuracy on bf16 MFMA.

#define N_GRAPHS 8192
#define BLOCK    256
#define NBLOCKS  (N_GRAPHS / 8)   // 1024: 8 groups per block

typedef __attribute__((ext_vector_type(8)))  short short8;    // 8 bf16 (4 VGPR)
typedef __attribute__((ext_vector_type(4)))  float floatx4;   // 16x16 C/D
typedef __attribute__((ext_vector_type(16))) float floatx16;  // 32x32 C/D

#define MFMA16(a, b, c) __builtin_amdgcn_mfma_f32_16x16x32_bf16((a), (b), (c), 0, 0, 0)
#define MFMA32(a, b, c) __builtin_amdgcn_mfma_f32_32x32x16_bf16((a), (b), (c), 0, 0, 0)

// ws frag-table layout (short8 units):
//   emb  hi: [kstep4][ntile4][lane64]            -> [0,    1024)
//   emb  lo:                                      -> [1024, 2048)
//   gcn l hi: 2048 + l*4096 + [kc4][nt8][lane64] -> 2048-frag slab
//   gcn l lo: hi + 2048
#define EMB_LO   1024
#define GCN_BASE 2048
#define GCN_LO   2048
#define N_FRAGS  10240            // * 16B = 160 KB of d_ws

__device__ __forceinline__ unsigned fbits(float x) {
  union { float f; unsigned u; } v; v.f = x; return v.u;
}
__device__ __forceinline__ float bitsf(unsigned u) {
  union { float f; unsigned u; } v; v.u = u; return v.f;
}
__device__ __forceinline__ void bsplit(float x, short& hi, short& lo) {
  unsigned hb = fbits(x) & 0xFFFF0000u;
  hi = (short)(hb >> 16);
  lo = (short)(fbits(x - bitsf(hb)) >> 16);
}
__device__ __forceinline__ float fast_tanh(float z) {
  float e = __expf(2.0f * z);
  return 1.0f - 2.0f / (e + 1.0f);
}

// ---- prep: f32 weights -> hi/lo bf16 frag tables (runs once per call) ----
__global__ __launch_bounds__(BLOCK) void gcn_prep(
    const float* __restrict__ w_emb, const float* __restrict__ w_gcn,
    short8* __restrict__ ws)
{
  int f = blockIdx.x * BLOCK + threadIdx.x;
  if (f >= 5120) return;
  const float* src;
  int hi_idx, lo_idx;
  if (f < 1024) {                       // emb table: 32x32x16 B layout
    int ks = f >> 8, t = (f >> 6) & 3, L = f & 63;
    int k0 = ks * 16 + (L >> 5) * 8;    // B[k][n]: k=(lane>>5)*8+j
    int n  = t * 32 + (L & 31);         //          n=lane&31
    src = w_emb + k0 * 128 + n;
    hi_idx = f; lo_idx = f + EMB_LO;
  } else {                              // gcn tables: 16x16x32 B layout
    int f2 = f - 1024;
    int l = f2 >> 11, r = f2 & 2047;
    int kc = r >> 9, nt = (r >> 6) & 7, L = r & 63;
    int k0 = kc * 32 + (L >> 4) * 8;    // B[k][n]: k=(lane>>4)*8+j
    int n  = nt * 16 + (L & 15);        //          n=lane&15
    src = w_gcn + l * 16384 + k0 * 128 + n;
    hi_idx = GCN_BASE + l * 4096 + r; lo_idx = hi_idx + GCN_LO;
  }
  short8 hi, lo;
  #pragma unroll
  for (int j = 0; j < 8; ++j) {
    short h, l_;
    bsplit(src[j * 128], h, l_);
    hi[j] = h; lo[j] = l_;
  }
  ws[hi_idx] = hi;
  ws[lo_idx] = lo;
}

__global__ __launch_bounds__(BLOCK, 4) void gcn_main(
    const float* __restrict__ obs,
    const float* __restrict__ b_emb,
    const float* __restrict__ b_gcn,
    const float* __restrict__ w_fc1,
    const float* __restrict__ b_fc1,
    const short8* __restrict__ tab,
    float* __restrict__ out)
{
  // stride 129: per-instr bank math verified conflict-free for all accesses
  __shared__ float sM[8][129];    // 8 block-local group means
  __shared__ float sH[8][129];    // 8 groups x 128 matvec outputs

  const int tid = threadIdx.x;
  const int w   = tid >> 6;          // wave = 2 groups
  const int L   = tid & 63;
  const int m32 = L & 31;            // 32-tile row / col
  const int kh  = L >> 5;            // k-half (32-wide frags)
  const int c16 = L & 15;            // 16-tile col / A row
  const int q   = L >> 4;            // 16-tile quad
  const int G0  = blockIdx.x * 8;    // block's first group (block-local g: 0..7)
  const int gw  = G0 + 2 * w;        // wave's first group

  // ---- obs A-operand loads (issued up front; 32 contiguous nodes/wave) ----
  // A[m=L&31][k = s*16 + kh*8 + j]
  const float* op = obs + (gw * 16 + m32) * 64 + kh * 8;
  float4 ov[4][2];
  #pragma unroll
  for (int s = 0; s < 4; ++s) {
    ov[s][0] = *(const float4*)(op + s * 16);
    ov[s][1] = *(const float4*)(op + s * 16 + 4);
  }

  // ---- embedding: x = obs @ w_emb + b_emb;  4 N-tiles of 32 cols ----
  floatx16 x[4];
  #pragma unroll
  for (int t = 0; t < 4; ++t) {
    float b = b_emb[t * 32 + m32];     // bias per column
    #pragma unroll
    for (int r = 0; r < 16; ++r) x[t][r] = b;
  }
  #pragma unroll
  for (int s = 0; s < 4; ++s) {
    float tmp[8] = {ov[s][0].x, ov[s][0].y, ov[s][0].z, ov[s][0].w,
                    ov[s][1].x, ov[s][1].y, ov[s][1].z, ov[s][1].w};
    short8 ah, al;
    #pragma unroll
    for (int j = 0; j < 8; ++j) {
      short h, l_;
      bsplit(tmp[j], h, l_);
      ah[j] = h; al[j] = l_;
    }
    #pragma unroll
    for (int t = 0; t < 4; ++t) {
      int idx = (s * 4 + t) * 64 + L;
      short8 bh = tab[idx];
      short8 bl = tab[idx + EMB_LO];
      x[t] = MFMA32(ah, bh, x[t]);
      x[t] = MFMA32(al, bh, x[t]);
      x[t] = MFMA32(ah, bl, x[t]);
    }
  }

  // ---- GCN layers: x = tanh((mean_g x) @ W_l + b_l + x) ----
  #pragma unroll 1
  for (int l = 0; l < 2; ++l) {
    // group means. 32x32 C rows: reg 0-7 -> rows 0-15 (group 2w),
    // reg 8-15 -> rows 16-31 (group 2w+1); xor32 folds the lane>>5 halves.
    #pragma unroll
    for (int t = 0; t < 4; ++t) {
      float s0 = 0.f, s1 = 0.f;
      #pragma unroll
      for (int r = 0; r < 8; ++r) { s0 += x[t][r]; s1 += x[t][r + 8]; }
      s0 += __shfl_xor(s0, 32);
      s1 += __shfl_xor(s1, 32);
      if (L < 32) {
        sM[2 * w][t * 32 + L]     = s0 * 0.0625f;
        sM[2 * w + 1][t * 32 + L] = s1 * 0.0625f;
      }
    }
    __syncthreads();

    // block-batched matvec: A rows = 8 group means (rows 8-15 zero);
    // wave w computes N-tiles {2w, 2w+1} (cols [32w, 32w+32))
    floatx4 h0 = {0.f, 0.f, 0.f, 0.f};
    floatx4 h1 = {0.f, 0.f, 0.f, 0.f};
    #pragma unroll
    for (int kc = 0; kc < 4; ++kc) {
      short8 ah, al;
      #pragma unroll
      for (int j = 0; j < 8; ++j) {
        int k = kc * 32 + q * 8 + j;
        float mv = sM[c16 & 7][k];     // 32 distinct banks, 2-lane broadcast
        if (c16 >= 8) mv = 0.f;
        short h, l_;
        bsplit(mv, h, l_);
        ah[j] = h; al[j] = l_;
      }
      int base = GCN_BASE + l * 4096 + kc * 8 * 64 + L;
      short8 bh0 = tab[base + (2 * w) * 64];
      short8 bl0 = tab[base + (2 * w) * 64 + GCN_LO];
      short8 bh1 = tab[base + (2 * w + 1) * 64];
      short8 bl1 = tab[base + (2 * w + 1) * 64 + GCN_LO];
      h0 = MFMA16(ah, bh0, h0); h0 = MFMA16(al, bh0, h0); h0 = MFMA16(ah, bl0, h0);
      h1 = MFMA16(ah, bh1, h1); h1 = MFMA16(al, bh1, h1); h1 = MFMA16(ah, bl1, h1);
    }
    // scatter h rows 0-7 (the 8 groups) to sH at this wave's 32 cols
    if (q < 2) {
      #pragma unroll
      for (int r = 0; r < 4; ++r) {
        sH[q * 4 + r][(2 * w) * 16 + c16]     = h0[r];
        sH[q * 4 + r][(2 * w + 1) * 16 + c16] = h1[r];
      }
    }
    __syncthreads();

    // residual + bias + tanh (x stays in 32x32 C layout)
    #pragma unroll
    for (int t = 0; t < 4; ++t) {
      float b  = b_gcn[l * 128 + t * 32 + m32];
      float zA = sH[2 * w][t * 32 + m32] + b;
      float zB = sH[2 * w + 1][t * 32 + m32] + b;
      #pragma unroll
      for (int r = 0; r < 8; ++r) {
        x[t][r]     = fast_tanh(x[t][r] + zA);
        x[t][r + 8] = fast_tanh(x[t][r + 8] + zB);
      }
    }
  }

  // ---- value head: out[g] = (1/16) sum_{node,col} x * w_fc1[col] + b ----
  float vA = 0.f, vB = 0.f;
  #pragma unroll
  for (int t = 0; t < 4; ++t) {
    float wf = w_fc1[t * 32 + m32];
    float sA = 0.f, sB = 0.f;
    #pragma unroll
    for (int r = 0; r < 8; ++r) { sA += x[t][r]; sB += x[t][r + 8]; }
    vA = fmaf(sA, wf, vA);
    vB = fmaf(sB, wf, vB);
  }
  #pragma unroll
  for (int d = 32; d >= 1; d >>= 1) {
    vA += __shfl_xor(vA, d);
    vB += __shfl_xor(vB, d);
  }
  if (L == 0) {
    float bf = b_fc1[0];
    out[gw]     = vA * 0.0625f + bf;
    out[gw + 1] = vB * 0.0625f + bf;
  }
}

extern "C" void kernel_launch(void* const* d_in, const int* in_sizes, int n_in,
                              void* d_out, int out_size, void* d_ws, size_t ws_size,
                              hipStream_t stream) {
  const float* obs    = (const float*)d_in[0];   // [131072, 64]
  const float* w_emb  = (const float*)d_in[1];   // [64, 128]
  const float* b_emb  = (const float*)d_in[2];   // [128]
  const float* w_gcn  = (const float*)d_in[3];   // [2, 128, 128]
  const float* b_gcn  = (const float*)d_in[4];   // [2, 128]
  const float* w_fc1  = (const float*)d_in[5];   // [128, 1]
  const float* b_fc1  = (const float*)d_in[6];   // [1]
  // d_in[7], d_in[8]: edge_src/edge_dst — redundant (deg==16 uniform)
  float* out = (float*)d_out;                    // [8192]
  short8* tab = (short8*)d_ws;                   // 160 KB frag tables

  gcn_prep<<<20, BLOCK, 0, stream>>>(w_emb, w_gcn, tab);
  gcn_main<<<NBLOCKS, BLOCK, 0, stream>>>(obs, b_emb, b_gcn, w_fc1, b_fc1,
                                          tab, out);
}

// Round 6
// 119.740 us; speedup vs baseline: 1.6964x; 1.0242x over previous
//
#include <hip/hip_runtime.h>

// GCNCriticNet, round 6.
// deg==16 uniform => GCN agg == group mean (edge arrays dead).
// prep: f32 weights -> hi/lo bf16 MFMA B-frag tables in d_ws (once/call).
// main: block = 8 groups, 4 waves; emb 32x32x16 (2 groups/wave); layer
// matvec block-batched via a cooperative bf16 A-table in LDS.
// R6 vs R5: __fdividef tanh (kills v_div_* sequences), LDS-cooperative
// A-frag build (kills per-wave bsplit), v_perm bf16 pair-packing, rolling
// prefetch to stay within 128 VGPR total (4 blocks/CU).

#define N_GRAPHS 8192
#define BLOCK    256
#define NBLOCKS  (N_GRAPHS / 8)   // 1024 blocks, 8 groups each

typedef __attribute__((ext_vector_type(8)))  short short8;    // 8 bf16
typedef __attribute__((ext_vector_type(4)))  float floatx4;   // 16x16 C/D
typedef __attribute__((ext_vector_type(16))) float floatx16;  // 32x32 C/D

#define MFMA16(a, b, c) __builtin_amdgcn_mfma_f32_16x16x32_bf16((a), (b), (c), 0, 0, 0)
#define MFMA32(a, b, c) __builtin_amdgcn_mfma_f32_32x32x16_bf16((a), (b), (c), 0, 0, 0)

// ws frag-table layout (short8 units):
//   emb hi [0,1024), emb lo [1024,2048)
//   gcn l: hi at 2048 + l*4096 + kc*512 + nt*64 + lane; lo at +2048
#define EMB_LO   1024
#define GCN_BASE 2048
#define GCN_LO   2048

union fragu { unsigned int u[4]; short8 s8; };

__device__ __forceinline__ unsigned fbits(float x) {
  union { float f; unsigned u; } v; v.f = x; return v.u;
}
__device__ __forceinline__ float bitsf(unsigned u) {
  union { float f; unsigned u; } v; v.u = u; return v.f;
}
__device__ __forceinline__ void bsplit(float x, short& hi, short& lo) {
  unsigned hb = fbits(x) & 0xFFFF0000u;
  hi = (short)(hb >> 16);
  lo = (short)(fbits(x - bitsf(hb)) >> 16);
}
// pack hi16 of (e0,e1) into one dword: bytes01=e0.hi16, bytes23=e1.hi16
__device__ __forceinline__ unsigned hpack(unsigned b_odd, unsigned b_even) {
  return __builtin_amdgcn_perm(b_odd, b_even, 0x07060302u);
}
// 8 f32 -> hi/lo bf16 frags via perm pair-packing (no insert chains)
__device__ __forceinline__ void mk_frags(float4 a, float4 b, short8& hi, short8& lo) {
  fragu H, L;
  H.u[0] = hpack(fbits(a.y), fbits(a.x));
  H.u[1] = hpack(fbits(a.w), fbits(a.z));
  H.u[2] = hpack(fbits(b.y), fbits(b.x));
  H.u[3] = hpack(fbits(b.w), fbits(b.z));
  float l0 = a.x - bitsf(fbits(a.x) & 0xFFFF0000u);
  float l1 = a.y - bitsf(fbits(a.y) & 0xFFFF0000u);
  float l2 = a.z - bitsf(fbits(a.z) & 0xFFFF0000u);
  float l3 = a.w - bitsf(fbits(a.w) & 0xFFFF0000u);
  float l4 = b.x - bitsf(fbits(b.x) & 0xFFFF0000u);
  float l5 = b.y - bitsf(fbits(b.y) & 0xFFFF0000u);
  float l6 = b.z - bitsf(fbits(b.z) & 0xFFFF0000u);
  float l7 = b.w - bitsf(fbits(b.w) & 0xFFFF0000u);
  L.u[0] = hpack(fbits(l1), fbits(l0));
  L.u[1] = hpack(fbits(l3), fbits(l2));
  L.u[2] = hpack(fbits(l5), fbits(l4));
  L.u[3] = hpack(fbits(l7), fbits(l6));
  hi = H.s8; lo = L.s8;
}
__device__ __forceinline__ float fast_tanh(float z) {
  float e = __expf(2.0f * z);
  return 1.0f - __fdividef(2.0f, e + 1.0f);   // rcp+mul, not v_div_* sequence
}

// ---- prep: one (frag,j) element per thread; 160 blocks x 256 ----
__global__ __launch_bounds__(BLOCK) void gcn_prep(
    const float* __restrict__ w_emb, const float* __restrict__ w_gcn,
    unsigned short* __restrict__ wsS)
{
  int idx = blockIdx.x * BLOCK + threadIdx.x;
  if (idx >= 40960) return;
  int f = idx >> 3, j = idx & 7;
  const float* src;
  int hi_f, lo_f;
  if (f < 1024) {                       // emb: 32x32x16 B layout
    int ks = f >> 8, t = (f >> 6) & 3, L = f & 63;
    int k0 = ks * 16 + (L >> 5) * 8;    // B[k][n]: k=(lane>>5)*8+j
    int n  = t * 32 + (L & 31);
    src = w_emb + k0 * 128 + n;
    hi_f = f; lo_f = f + EMB_LO;
  } else {                              // gcn: 16x16x32 B layout
    int f2 = f - 1024;
    int l = f2 >> 11, r = f2 & 2047;
    int kc = r >> 9, nt = (r >> 6) & 7, L = r & 63;
    int k0 = kc * 32 + (L >> 4) * 8;    // B[k][n]: k=(lane>>4)*8+j
    int n  = nt * 16 + (L & 15);
    src = w_gcn + l * 16384 + k0 * 128 + n;
    hi_f = GCN_BASE + l * 4096 + r; lo_f = hi_f + GCN_LO;
  }
  short h, l_;
  bsplit(src[j * 128], h, l_);
  wsS[hi_f * 8 + j] = (unsigned short)h;
  wsS[lo_f * 8 + j] = (unsigned short)l_;
}

__global__ __launch_bounds__(BLOCK, 4) void gcn_main(
    const float* __restrict__ obs,
    const float* __restrict__ b_emb,
    const float* __restrict__ b_gcn,
    const float* __restrict__ w_fc1,
    const float* __restrict__ b_fc1,
    const short8* __restrict__ tab,
    float* __restrict__ out)
{
  // A-frag table: [hl][kc4][row16][40 shorts] (row stride 80B, 16B-aligned;
  // bank math: word = 20*c16 + 4*q (+const) -> max 2-way alias = free)
  __shared__ short sA[2 * 4 * 16 * 40];   // 10240 B
  __shared__ float sH[8][129];            // matvec outputs per group

  const int tid = threadIdx.x;
  const int w   = tid >> 6;
  const int L   = tid & 63;
  const int m32 = L & 31;
  const int kh  = L >> 5;
  const int c16 = L & 15;
  const int q   = L >> 4;
  const int gw  = blockIdx.x * 8 + 2 * w;   // wave's first group

  // zero A-table rows 8-15 once (disjoint from rows 0-7 the layers write)
  {
    unsigned int* za = (unsigned int*)sA;   // 1280 dwords in rows 8-15
    #pragma unroll
    for (int jz = 0; jz < 5; ++jz) {
      int i   = tid + 256 * jz;
      int tb_ = i / 160;                    // [hl][kc] region 0..7
      int rm  = i - tb_ * 160;
      int rr  = rm / 20, cw = rm - rr * 20;
      za[tb_ * 320 + (rr + 8) * 20 + cw] = 0;
    }
  }

  // ---- embedding: x = obs @ w_emb + b_emb; 4 N-tiles of 32 cols ----
  // A[m=L&31][k = s*16 + kh*8 + j]; rolling obs prefetch (distance 2)
  const float* op = obs + (gw * 16 + m32) * 64 + kh * 8;
  float4 oa0 = *(const float4*)(op);
  float4 oa1 = *(const float4*)(op + 4);
  float4 ob0 = *(const float4*)(op + 16);
  float4 ob1 = *(const float4*)(op + 20);

  floatx16 x[4];
  #pragma unroll
  for (int t = 0; t < 4; ++t) {
    float b = b_emb[t * 32 + m32];
    #pragma unroll
    for (int r = 0; r < 16; ++r) x[t][r] = b;
  }

  #pragma unroll
  for (int s = 0; s < 4; ++s) {
    short8 ah, al;
    mk_frags(oa0, oa1, ah, al);
    oa0 = ob0; oa1 = ob1;
    if (s < 2) {                         // prefetch s+2
      ob0 = *(const float4*)(op + (s + 2) * 16);
      ob1 = *(const float4*)(op + (s + 2) * 16 + 4);
    }
    #pragma unroll
    for (int t = 0; t < 4; ++t) {
      int idx = (s * 4 + t) * 64 + L;
      short8 bh = tab[idx];
      short8 bl = tab[idx + EMB_LO];
      x[t] = MFMA32(ah, bh, x[t]);
      x[t] = MFMA32(al, bh, x[t]);
      x[t] = MFMA32(ah, bl, x[t]);
    }
  }

  // ---- GCN layers: x = tanh((mean_g x) @ W_l + b_l + x) ----
  #pragma unroll 1
  for (int l = 0; l < 2; ++l) {
    const short8* t0 = tab + GCN_BASE + l * 4096 + (2 * w) * 64 + L;
    const short8* t1 = t0 + 64;
    // kc=0 B-frags prefetch (hides L2 latency under mean build + barrier)
    short8 cbh0 = t0[0], cbh1 = t1[0];
    short8 cbl0 = t0[GCN_LO], cbl1 = t1[GCN_LO];

    // means -> packed bf16 hi/lo A-table rows 2w, 2w+1 (cooperative):
    // lanes<32 write hi table, lanes>=32 write lo; even cols pack pairs.
    #pragma unroll
    for (int t = 0; t < 4; ++t) {
      float s0 = x[t][0], s1 = x[t][8];
      #pragma unroll
      for (int r = 1; r < 8; ++r) { s0 += x[t][r]; s1 += x[t][r + 8]; }
      s0 += __shfl_xor(s0, 32);
      s1 += __shfl_xor(s1, 32);
      s0 *= 0.0625f; s1 *= 0.0625f;
      #pragma unroll
      for (int rr = 0; rr < 2; ++rr) {
        float v = rr ? s1 : s0;
        unsigned hb = fbits(v) & 0xFFFF0000u;
        unsigned vb = (kh == 0) ? hb : fbits(v - bitsf(hb));
        unsigned nb = (unsigned)__shfl_xor((int)vb, 1);
        unsigned pw = hpack(nb, vb);       // (even col, odd col)
        if ((m32 & 1) == 0) {
          int si = kh * 2560 + t * 640 + (2 * w + rr) * 40
                 + (m32 >> 3) * 8 + (m32 & 7);
          *(unsigned int*)&sA[si] = pw;
        }
      }
    }
    __syncthreads();

    // block-batched matvec: A rows = 8 means (rows 8-15 zero);
    // wave w -> N-tiles {2w, 2w+1}; rolling next-kc B prefetch
    floatx4 h0 = {0.f, 0.f, 0.f, 0.f};
    floatx4 h1 = {0.f, 0.f, 0.f, 0.f};
    #pragma unroll
    for (int kc = 0; kc < 4; ++kc) {
      short8 ah = *(const short8*)&sA[kc * 640 + c16 * 40 + q * 8];
      short8 al = *(const short8*)&sA[2560 + kc * 640 + c16 * 40 + q * 8];
      short8 nbh0, nbh1, nbl0, nbl1;
      if (kc < 3) {
        nbh0 = t0[(kc + 1) * 512];
        nbh1 = t1[(kc + 1) * 512];
        nbl0 = t0[(kc + 1) * 512 + GCN_LO];
        nbl1 = t1[(kc + 1) * 512 + GCN_LO];
      }
      h0 = MFMA16(ah, cbh0, h0); h1 = MFMA16(ah, cbh1, h1);
      h0 = MFMA16(al, cbh0, h0); h1 = MFMA16(al, cbh1, h1);
      h0 = MFMA16(ah, cbl0, h0); h1 = MFMA16(ah, cbl1, h1);
      cbh0 = nbh0; cbh1 = nbh1; cbl0 = nbl0; cbl1 = nbl1;
    }
    // scatter rows 0-7 (the 8 groups) to sH at this wave's 32 cols
    if (q < 2) {
      #pragma unroll
      for (int r = 0; r < 4; ++r) {
        sH[q * 4 + r][(2 * w) * 16 + c16]     = h0[r];
        sH[q * 4 + r][(2 * w + 1) * 16 + c16] = h1[r];
      }
    }
    __syncthreads();

    // residual + bias + tanh (x stays in 32x32 C layout)
    #pragma unroll
    for (int t = 0; t < 4; ++t) {
      float b  = b_gcn[l * 128 + t * 32 + m32];
      float zA = sH[2 * w][t * 32 + m32] + b;
      float zB = sH[2 * w + 1][t * 32 + m32] + b;
      #pragma unroll
      for (int r = 0; r < 8; ++r) {
        x[t][r]     = fast_tanh(x[t][r] + zA);
        x[t][r + 8] = fast_tanh(x[t][r + 8] + zB);
      }
    }
  }

  // ---- value head: out[g] = (1/16) sum_{node,col} x * w_fc1[col] + b ----
  float vA = 0.f, vB = 0.f;
  #pragma unroll
  for (int t = 0; t < 4; ++t) {
    float wf = w_fc1[t * 32 + m32];
    float sA_ = 0.f, sB_ = 0.f;
    #pragma unroll
    for (int r = 0; r < 8; ++r) { sA_ += x[t][r]; sB_ += x[t][r + 8]; }
    vA = fmaf(sA_, wf, vA);
    vB = fmaf(sB_, wf, vB);
  }
  #pragma unroll
  for (int d = 32; d >= 1; d >>= 1) {
    vA += __shfl_xor(vA, d);
    vB += __shfl_xor(vB, d);
  }
  if (L == 0) {
    float bf = b_fc1[0];
    out[gw]     = vA * 0.0625f + bf;
    out[gw + 1] = vB * 0.0625f + bf;
  }
}

extern "C" void kernel_launch(void* const* d_in, const int* in_sizes, int n_in,
                              void* d_out, int out_size, void* d_ws, size_t ws_size,
                              hipStream_t stream) {
  const float* obs    = (const float*)d_in[0];   // [131072, 64]
  const float* w_emb  = (const float*)d_in[1];   // [64, 128]
  const float* b_emb  = (const float*)d_in[2];   // [128]
  const float* w_gcn  = (const float*)d_in[3];   // [2, 128, 128]
  const float* b_gcn  = (const float*)d_in[4];   // [2, 128]
  const float* w_fc1  = (const float*)d_in[5];   // [128, 1]
  const float* b_fc1  = (const float*)d_in[6];   // [1]
  // d_in[7], d_in[8]: edge_src/edge_dst — redundant (deg==16 uniform)
  float* out = (float*)d_out;                    // [8192]

  gcn_prep<<<160, BLOCK, 0, stream>>>(w_emb, w_gcn, (unsigned short*)d_ws);
  gcn_main<<<NBLOCKS, BLOCK, 0, stream>>>(obs, b_emb, b_gcn, w_fc1, b_fc1,
                                          (const short8*)d_ws, out);
}